// Round 12
// baseline (154.259 us; speedup 1.0000x reference)
//
#include <hip/hip_runtime.h>
#include <math.h>

// Problem constants
#define N_TOK 32768
#define KCB   4096
#define SPLITS 6
// per-split tile counts (even): {44,44,42,42,42,42}, sum = 256 tiles = 4096 codes

// Output layout (flat float32)
#define OFF_ZQST   0
#define OFF_ZQ     2097152
#define OFF_IDX    4194304
#define OFF_STATS  4227072
#define OFF_NEWEMB 4227074
#define OFF_NEWCS  4489218
#define OFF_NEWEMA 4493314

// Workspace layout (bytes)
#define WS_FN       0          // 8388608
#define WS_ESUM     8388608    // 1048576 (zeroed by k_prep)
#define WS_USAGE    9437184    // 16384   (zeroed by k_prep)
#define WS_CNTS     9453568    // 1024    (zeroed by k_prep; cnts[0]=fullcnt, scal[] at +16)
#define WS_FULLKEY  9454592    // 262144  (init by k_merge_fix)
#define WS_EHI      9716736    // 524288
#define WS_ELO      10241024   // 524288
#define WS_PK1      10765312   // 786432 (6 splits)
#define WS_PK2      11551744   // 786432
#define WS_IDXW     12338176   // 131072
#define WS_RIDX     12469248   // 16384
#define WS_FULL     12485632   // 131072
#define WS_FNHI     12616704   // 4194304 (pre-split bf16 hi of fn*0.25)
#define WS_FNLO     16811008   // 4194304 (bf16 lo)
// total workspace = 21005312

// 131072 keys = 128 x-ulps dot gap (calibrated at 0.125 scale; 2x margin at 0.25)
#define THRKEY 131072u
// danger margin for hidden-3rd-in-split
#define DGRKEY 98304u

typedef __attribute__((ext_vector_type(8))) short short8;
typedef __attribute__((ext_vector_type(4))) short short4v;
typedef __attribute__((ext_vector_type(4))) float float4v;
typedef __attribute__((ext_vector_type(4))) int int4v;

__device__ __forceinline__ float wave_sum(float v) {
#pragma unroll
  for (int off = 32; off > 0; off >>= 1) v += __shfl_xor(v, off, 64);
  return v;
}

// round-to-nearest-even f32 -> bf16 bits
__device__ __forceinline__ unsigned short f2bf(float f) {
  unsigned u = __float_as_uint(f);
  unsigned r = (u + 0x7fffu + ((u >> 16) & 1u)) >> 16;
  return (unsigned short)r;
}
__device__ __forceinline__ float bf2f(unsigned short h) {
  return __uint_as_float(((unsigned)h) << 16);
}

// async global->LDS 16B/lane (dest = wave-uniform base + lane*16)
typedef const __attribute__((address_space(1))) unsigned int* gas_ptr;
typedef __attribute__((address_space(3))) unsigned int* las_ptr;
__device__ __forceinline__ void gl_lds16(const void* g, void* l) {
  __builtin_amdgcn_global_load_lds((gas_ptr)g, (las_ptr)l, 16, 0, 0);
}

// exact top-2 running update: run2' = median(run1, run2, kb)  [run1 >= run2]
__device__ __forceinline__ unsigned med3u(unsigned a, unsigned b, unsigned c) {
  unsigned r;
  asm("v_med3_u32 %0, %1, %2, %3" : "=v"(r) : "v"(a), "v"(b), "v"(c));
  return r;
}

// ---------------- Threefry-2x32 (20 rounds), bit-exact vs JAX ----------------
__device__ __forceinline__ unsigned rotl32(unsigned x, int d) {
  return (x << d) | (x >> (32 - d));
}
__device__ __forceinline__ void tf2x32(unsigned k0, unsigned k1,
                                       unsigned x0, unsigned x1,
                                       unsigned& o0, unsigned& o1) {
  unsigned ks2 = k0 ^ k1 ^ 0x1BD11BDAu;
  unsigned v0 = x0 + k0, v1 = x1 + k1;
  v0 += v1; v1 = rotl32(v1, 13) ^ v0;
  v0 += v1; v1 = rotl32(v1, 15) ^ v0;
  v0 += v1; v1 = rotl32(v1, 26) ^ v0;
  v0 += v1; v1 = rotl32(v1, 6) ^ v0;
  v0 += k1; v1 += ks2 + 1u;
  v0 += v1; v1 = rotl32(v1, 17) ^ v0;
  v0 += v1; v1 = rotl32(v1, 29) ^ v0;
  v0 += v1; v1 = rotl32(v1, 16) ^ v0;
  v0 += v1; v1 = rotl32(v1, 24) ^ v0;
  v0 += ks2; v1 += k0 + 2u;
  v0 += v1; v1 = rotl32(v1, 13) ^ v0;
  v0 += v1; v1 = rotl32(v1, 15) ^ v0;
  v0 += v1; v1 = rotl32(v1, 26) ^ v0;
  v0 += v1; v1 = rotl32(v1, 6) ^ v0;
  v0 += k0; v1 += k1 + 3u;
  v0 += v1; v1 = rotl32(v1, 17) ^ v0;
  v0 += v1; v1 = rotl32(v1, 29) ^ v0;
  v0 += v1; v1 = rotl32(v1, 16) ^ v0;
  v0 += v1; v1 = rotl32(v1, 24) ^ v0;
  v0 += k1; v1 += ks2 + 4u;
  v0 += v1; v1 = rotl32(v1, 13) ^ v0;
  v0 += v1; v1 = rotl32(v1, 15) ^ v0;
  v0 += v1; v1 = rotl32(v1, 26) ^ v0;
  v0 += v1; v1 = rotl32(v1, 6) ^ v0;
  v0 += ks2; v1 += k0 + 5u;
  o0 = v0; o1 = v1;
}

// ---- fused prep (float4-vectorized, G13): norm | emb hi/lo | ridx |
//      zero | ema_cs sum (scal[2]) | fn hi/lo bf16 pre-split ----
__global__ __launch_bounds__(256) void k_prep(const float* __restrict__ z_e,
                                              const float* __restrict__ emb,
                                              const float* __restrict__ ema_cs,
                                              float* __restrict__ fn,
                                              unsigned short* __restrict__ fnhi,
                                              unsigned short* __restrict__ fnlo,
                                              unsigned short* __restrict__ ehi,
                                              unsigned short* __restrict__ elo,
                                              int* __restrict__ ridx,
                                              int* __restrict__ zbase,
                                              float* __restrict__ scal) {
  __shared__ float rC[4];
  int b = blockIdx.x;
  int t = threadIdx.x;
  if (b < 2048) {
    int wave = t >> 6, lane = t & 63;
    int grp = lane >> 4, l = lane & 15;          // 4 rows/wave, 16 lanes/row
    int n = b * 16 + wave * 4 + grp;
    float4v v = ((const float4v*)(z_e + n * 64))[l];
    // exact replica of the old 64-lane butterfly tree
    float4v p;
#pragma unroll
    for (int j = 0; j < 4; j++) p[j] = v[j] * v[j];
#pragma unroll
    for (int j = 0; j < 4; j++) p[j] += __shfl_xor(p[j], 8, 64);   // elems +-32
#pragma unroll
    for (int j = 0; j < 4; j++) p[j] += __shfl_xor(p[j], 4, 64);   // +-16
#pragma unroll
    for (int j = 0; j < 4; j++) p[j] += __shfl_xor(p[j], 2, 64);   // +-8
#pragma unroll
    for (int j = 0; j < 4; j++) p[j] += __shfl_xor(p[j], 1, 64);   // +-4
    float t0 = p[0] + p[2], t1 = p[1] + p[3];                      // +-2
    float ss = t0 + t1;                                            // +-1
    float d = fmaxf(sqrtf(ss), 1e-8f);
    float4v o;
#pragma unroll
    for (int j = 0; j < 4; j++) o[j] = v[j] / d;
    ((float4v*)(fn + n * 64))[l] = o;
    // bf16 hi/lo split of o*0.25 (exact pow2), same ops k_dots used
    short4v fh, fl2;
#pragma unroll
    for (int j = 0; j < 4; j++) {
      float f = o[j] * 0.25f;
      unsigned short hu = f2bf(f);
      fh[j] = (short)hu;
      fl2[j] = (short)f2bf(f - bf2f(hu));
    }
    ((short4v*)(fnhi + n * 64))[l] = fh;
    ((short4v*)(fnlo + n * 64))[l] = fl2;
  } else if (b < 2304) {
    int i = (b - 2048) * 1024 + t * 4;
    float4v x = *(const float4v*)(emb + i);
    short4v hh, ll;
#pragma unroll
    for (int j = 0; j < 4; j++) {
      unsigned short hu = f2bf(x[j]);
      hh[j] = (short)hu;
      ll[j] = (short)f2bf(x[j] - bf2f(hu));
    }
    *(short4v*)(ehi + i) = hh;
    *(short4v*)(elo + i) = ll;
  } else if (b < 2312) {
    int j = (b - 2304) * 256 + t;  // 0..2047
    unsigned a0, b0, a1, b1;
    tf2x32(0u, 1u, 0u, 2u, a0, b0);
    tf2x32(0u, 1u, 1u, 3u, a1, b1);
    unsigned o0, o1;
    tf2x32(b0, b1, (unsigned)j, (unsigned)(j + 2048), o0, o1);
    ridx[j] = (int)(o0 & 32767u);
    ridx[j + 2048] = (int)(o1 & 32767u);
  } else {
    // zero esum+usage+cnts/scal = 266496 ints = 66624 int4 -> blocks 2312..2572
    int i4 = (b - 2312) * 256 + t;
    if (i4 < 66624) ((int4v*)zbase)[i4] = (int4v){0, 0, 0, 0};
    if (b == 2572) {
      __syncthreads();  // zeros of this block's range (incl. scal) are done
      float s = 0.f;
#pragma unroll
      for (int j = 0; j < 16; j++) s += ema_cs[j * 256 + t];
      s = wave_sum(s);
      int w = t >> 6, lane = t & 63;
      if (lane == 0) rC[w] = s;
      __syncthreads();
      if (t == 0) scal[2] = 0.99f * (rC[0] + rC[1] + rC[2] + rC[3]) + 327.68f;
    }
  }
}

// ---------------- MFMA dots + per-split packed top-2 ------------------------
// 3-pass bf16 double-double (A scaled 0.25): lo*Hi + hi*Lo + hi*Hi.
// R12 occupancy fix: R11's fragment hoist cut regs to 80 -> HW now allows 6
// waves/SIMD, but the 768-block grid gave only 3.  Split each split's pair
// range in half INSIDE the block: block = 128 queries, wave = (qg, half);
// wave (qg,h) scans half h's pairs for queries qg*64..+64.  Grid x2 -> 1536
// blocks; LDS 32KB/block -> 5 resident blocks/CU (20 waves).  Exact cross-half
// top-2 merge per block (same algebra as k_merge_fix); key packing is
// split-relative so pk1/pk2 and all downstream kernels are unchanged.
// 42-tile splits give half B 10 pairs vs 11: fixed 11-trip loop with
// wave-uniform 'active' masking keeps the barrier cadence identical.
// LAUNCH BOUNDS LESSON (R2-R4): (256,3) -> no spill.  Do not tighten.
__global__ __launch_bounds__(256, 3) void k_dots(const unsigned short* __restrict__ fnhi,
                                                 const unsigned short* __restrict__ fnlo,
                                                 const unsigned short* __restrict__ ehi,
                                                 const unsigned short* __restrict__ elo,
                                                 unsigned* __restrict__ pk1,
                                                 unsigned* __restrict__ pk2) {
  __shared__ unsigned short lds_b[2][2][2][2][1024];  // [half][buf][tile][hi/lo][2KB]
  int t = threadIdx.x;
  int wave = t >> 6, lane = t & 63;
  int g = lane >> 4, n = lane & 15;
  int qg = wave >> 1, half = wave & 1;
  int qw = blockIdx.x * 128 + qg * 64;    // wave's 64 queries
  int split = blockIdx.y;                 // 0..5
  int nt16 = (split < 2) ? 704 : 672;     // codes in this split
  int tstart16 = (split < 3) ? 704 * split : 672 * split + 64;
  int ntiles = nt16 >> 4;                 // 44 or 42 (even)
  int npairs = ntiles >> 1;               // 22 or 21
  int p0 = half * 11;
  int pend = half ? npairs : 11;          // half0: 11 pairs; half1: 11 or 10

  // A fragments: direct short8 loads of the pre-split hi/lo
  short8 ahi[4][2], alo[4][2];
#pragma unroll
  for (int s = 0; s < 4; s++)
#pragma unroll
    for (int ks = 0; ks < 2; ks++) {
      int off = (qw + s * 16 + n) * 64 + ks * 32 + g * 8;
      ahi[s][ks] = *(const short8*)(fnhi + off);
      alo[s][ks] = *(const short8*)(fnlo + off);
    }

  unsigned run1[4][4], run2[4][4];
#pragma unroll
  for (int s = 0; s < 4; s++)
#pragma unroll
    for (int r = 0; r < 4; r++) { run1[s][r] = 0u; run2[s][r] = 0u; }

  const float hiclamp = __uint_as_float(0x3F9FFFFFu);  // 1.25 - 1ulp

  // staging role: wave stages stream (hi if qg==0 else lo) for its half;
  // both tiles of the pair; 4 x 1KB gl_lds16 per wave per pair.
  int shl = qg;
  const unsigned short* sbase = shl ? elo : ehi;
  int c0 = lane ^ ((lane >> 3) & 7);  // inverse-swizzled source chunk (involution)

#define STAGE(BUF, PAIR)                                                        \
    {                                                                           \
      const unsigned short* sg0 =                                               \
          sbase + (tstart16 + ((PAIR) * 2 + 0) * 16) * 64;                      \
      const unsigned short* sg1 =                                               \
          sbase + (tstart16 + ((PAIR) * 2 + 1) * 16) * 64;                      \
      gl_lds16(sg0 + c0 * 8, &lds_b[half][BUF][0][shl][0]);                     \
      gl_lds16(sg0 + 512 + c0 * 8, &lds_b[half][BUF][0][shl][512]);             \
      gl_lds16(sg1 + c0 * 8, &lds_b[half][BUF][1][shl][0]);                     \
      gl_lds16(sg1 + 512 + c0 * 8, &lds_b[half][BUF][1][shl][512]);             \
    }

  // swizzled read slots (shorts): lane (g,n) wants linear chunk n*8+g (+4 for H1)
  int sh0 = (n * 8 + (g ^ (n & 7))) * 8;
  int sh1 = (n * 8 + ((g + 4) ^ (n & 7))) * 8;

#define MFMA_BLOCK(H0, H1, L0, L1)                                              \
    float4v a0 = (float4v){1.125f, 1.125f, 1.125f, 1.125f};                     \
    float4v a1 = a0, a2 = a0, a3 = a0;                                          \
    a0 = __builtin_amdgcn_mfma_f32_16x16x32_bf16(alo[0][0], H0, a0, 0, 0, 0);   \
    a1 = __builtin_amdgcn_mfma_f32_16x16x32_bf16(alo[1][0], H0, a1, 0, 0, 0);   \
    a2 = __builtin_amdgcn_mfma_f32_16x16x32_bf16(alo[2][0], H0, a2, 0, 0, 0);   \
    a3 = __builtin_amdgcn_mfma_f32_16x16x32_bf16(alo[3][0], H0, a3, 0, 0, 0);   \
    a0 = __builtin_amdgcn_mfma_f32_16x16x32_bf16(alo[0][1], H1, a0, 0, 0, 0);   \
    a1 = __builtin_amdgcn_mfma_f32_16x16x32_bf16(alo[1][1], H1, a1, 0, 0, 0);   \
    a2 = __builtin_amdgcn_mfma_f32_16x16x32_bf16(alo[2][1], H1, a2, 0, 0, 0);   \
    a3 = __builtin_amdgcn_mfma_f32_16x16x32_bf16(alo[3][1], H1, a3, 0, 0, 0);   \
    a0 = __builtin_amdgcn_mfma_f32_16x16x32_bf16(ahi[0][0], L0, a0, 0, 0, 0);   \
    a1 = __builtin_amdgcn_mfma_f32_16x16x32_bf16(ahi[1][0], L0, a1, 0, 0, 0);   \
    a2 = __builtin_amdgcn_mfma_f32_16x16x32_bf16(ahi[2][0], L0, a2, 0, 0, 0);   \
    a3 = __builtin_amdgcn_mfma_f32_16x16x32_bf16(ahi[3][0], L0, a3, 0, 0, 0);   \
    a0 = __builtin_amdgcn_mfma_f32_16x16x32_bf16(ahi[0][1], L1, a0, 0, 0, 0);   \
    a1 = __builtin_amdgcn_mfma_f32_16x16x32_bf16(ahi[1][1], L1, a1, 0, 0, 0);   \
    a2 = __builtin_amdgcn_mfma_f32_16x16x32_bf16(ahi[2][1], L1, a2, 0, 0, 0);   \
    a3 = __builtin_amdgcn_mfma_f32_16x16x32_bf16(ahi[3][1], L1, a3, 0, 0, 0);   \
    a0 = __builtin_amdgcn_mfma_f32_16x16x32_bf16(ahi[0][0], H0, a0, 0, 0, 0);   \
    a1 = __builtin_amdgcn_mfma_f32_16x16x32_bf16(ahi[1][0], H0, a1, 0, 0, 0);   \
    a2 = __builtin_amdgcn_mfma_f32_16x16x32_bf16(ahi[2][0], H0, a2, 0, 0, 0);   \
    a3 = __builtin_amdgcn_mfma_f32_16x16x32_bf16(ahi[3][0], H0, a3, 0, 0, 0);   \
    a0 = __builtin_amdgcn_mfma_f32_16x16x32_bf16(ahi[0][1], H1, a0, 0, 0, 0);   \
    a1 = __builtin_amdgcn_mfma_f32_16x16x32_bf16(ahi[1][1], H1, a1, 0, 0, 0);   \
    a2 = __builtin_amdgcn_mfma_f32_16x16x32_bf16(ahi[2][1], H1, a2, 0, 0, 0);   \
    a3 = __builtin_amdgcn_mfma_f32_16x16x32_bf16(ahi[3][1], H1, a3, 0, 0, 0);

#define SELECT_BLOCK(KT)                                                        \
    {                                                                           \
      unsigned invb = (unsigned)(nt16 - 1 - (KT) * 16 - n);                     \
      _Pragma("unroll") for (int r = 0; r < 4; r++) {                           \
        float x0 = __builtin_amdgcn_fmed3f(a0[r], 1.0f, hiclamp);               \
        unsigned kb0 = (__float_as_uint(x0) << 10) + invb;                      \
        run2[0][r] = med3u(run1[0][r], run2[0][r], kb0);                        \
        run1[0][r] = max(run1[0][r], kb0);                                      \
        float x1 = __builtin_amdgcn_fmed3f(a1[r], 1.0f, hiclamp);               \
        unsigned kb1 = (__float_as_uint(x1) << 10) + invb;                      \
        run2[1][r] = med3u(run1[1][r], run2[1][r], kb1);                        \
        run1[1][r] = max(run1[1][r], kb1);                                      \
        float x2 = __builtin_amdgcn_fmed3f(a2[r], 1.0f, hiclamp);               \
        unsigned kb2 = (__float_as_uint(x2) << 10) + invb;                      \
        run2[2][r] = med3u(run1[2][r], run2[2][r], kb2);                        \
        run1[2][r] = max(run1[2][r], kb2);                                      \
        float x3 = __builtin_amdgcn_fmed3f(a3[r], 1.0f, hiclamp);               \
        unsigned kb3 = (__float_as_uint(x3) << 10) + invb;                      \
        run2[3][r] = med3u(run1[3][r], run2[3][r], kb3);                        \
        run1[3][r] = max(run1[3][r], kb3);                                      \
      }                                                                         \
    }

  STAGE(0, p0)  // every half has >= 1 pair
  __syncthreads();
  int bb = 0;
#pragma unroll 1
  for (int pr = 0; pr < 11; pr++) {
    int pair = p0 + pr;
    bool act = pair < pend;  // wave-uniform
    if (act && pair + 1 < pend) STAGE(bb ^ 1, pair + 1)
    if (act) {
      {
        short8 H0 = *(const short8*)&lds_b[half][bb][0][0][sh0];
        short8 H1 = *(const short8*)&lds_b[half][bb][0][0][sh1];
        short8 L0 = *(const short8*)&lds_b[half][bb][0][1][sh0];
        short8 L1 = *(const short8*)&lds_b[half][bb][0][1][sh1];
        MFMA_BLOCK(H0, H1, L0, L1)
        SELECT_BLOCK(pair * 2)
      }
      {
        short8 H0 = *(const short8*)&lds_b[half][bb][1][0][sh0];
        short8 H1 = *(const short8*)&lds_b[half][bb][1][0][sh1];
        short8 L0 = *(const short8*)&lds_b[half][bb][1][1][sh0];
        short8 L1 = *(const short8*)&lds_b[half][bb][1][1][sh1];
        MFMA_BLOCK(H0, H1, L0, L1)
        SELECT_BLOCK(pair * 2 + 1)
      }
    }
    __syncthreads();  // all waves, every trip: uniform barrier cadence
    bb ^= 1;
  }
#undef MFMA_BLOCK
#undef SELECT_BLOCK
#undef STAGE

  // butterfly top-2 merge across the 16 n-lanes (within this wave's half)
#pragma unroll
  for (int off = 1; off <= 8; off <<= 1) {
#pragma unroll
    for (int s = 0; s < 4; s++)
#pragma unroll
      for (int r = 0; r < 4; r++) {
        unsigned o1 = (unsigned)__shfl_xor((int)run1[s][r], off, 64);
        unsigned o2 = (unsigned)__shfl_xor((int)run2[s][r], off, 64);
        run2[s][r] = max(min(run1[s][r], o1), max(run2[s][r], o2));
        run1[s][r] = max(run1[s][r], o1);
      }
  }

  // exact cross-half merge via reused LDS (loop's last barrier drained reads)
  unsigned* mb = (unsigned*)lds_b;  // 512 u32 used of 32KB
  if (n == 0) {
#pragma unroll
    for (int s = 0; s < 4; s++)
#pragma unroll
      for (int r = 0; r < 4; r++) {
        int ql = s * 16 + g * 4 + r;  // 0..63, unique per (s,g,r)
        mb[wave * 64 + ql] = run1[s][r];
        mb[256 + wave * 64 + ql] = run2[s][r];
      }
  }
  __syncthreads();
  if (t < 128) {
    int qg2 = t >> 6, ql = t & 63;
    unsigned k1a = mb[(qg2 * 2 + 0) * 64 + ql];
    unsigned k1b = mb[(qg2 * 2 + 1) * 64 + ql];
    unsigned k2a = mb[256 + (qg2 * 2 + 0) * 64 + ql];
    unsigned k2b = mb[256 + (qg2 * 2 + 1) * 64 + ql];
    unsigned b1 = max(k1a, k1b);
    unsigned b2 = max(min(k1a, k1b), max(k2a, k2b));
    int q = blockIdx.x * 128 + qg2 * 64 + ql;
    pk1[split * N_TOK + q] = b1;
    pk2[split * N_TOK + q] = b2;
  }
}

// ---- merge splits + in-kernel fp64 rescore of 12 candidates for flagged ----
// danger (possible hidden 3rd-in-split near max) -> rare full-rescan list.
__global__ __launch_bounds__(256) void k_merge_fix(const unsigned* __restrict__ pk1,
                                                   const unsigned* __restrict__ pk2,
                                                   const float* __restrict__ fn,
                                                   const float* __restrict__ emb,
                                                   int* __restrict__ idxw,
                                                   int* __restrict__ cnts,
                                                   int* __restrict__ full,
                                                   unsigned long long* __restrict__ fullkey) {
  __shared__ int nfl;
  __shared__ int fl[256][13];
  int t = threadIdx.x;
  if (t == 0) nfl = 0;
  __syncthreads();
  int q = blockIdx.x * 256 + t;
  unsigned k1v[SPLITS], k2v[SPLITS];
  unsigned b1 = 0u, b2 = 0u;
  int s1 = 0;
#pragma unroll
  for (int s = 0; s < SPLITS; s++) {
    unsigned k1 = pk1[s * N_TOK + q];
    unsigned k2 = pk2[s * N_TOK + q];
    k1v[s] = k1;
    k2v[s] = k2;
    b2 = max(b2, min(b1, k1));
    b2 = max(b2, k2);
    if (k1 > b1) { b1 = k1; s1 = s; }
  }
  int nt16s = (s1 < 2) ? 704 : 672;
  int ts16 = (s1 < 3) ? 704 * s1 : 672 * s1 + 64;
  idxw[q] = ts16 + nt16s - 1 - (int)(b1 & 1023u);
  fullkey[q] = 0ull;
  bool danger = false;
#pragma unroll
  for (int s = 0; s < SPLITS; s++) danger |= (k2v[s] + DGRKEY > b1);
  if (danger) {
    int p = atomicAdd(&cnts[0], 1);
    full[p] = q;
  } else if (b1 - b2 < THRKEY) {
    int p = atomicAdd(&nfl, 1);
    fl[p][0] = q;
#pragma unroll
    for (int s = 0; s < SPLITS; s++) {
      int nt = (s < 2) ? 704 : 672;
      int tss = (s < 3) ? 704 * s : 672 * s + 64;
      fl[p][1 + s] = tss + nt - 1 - (int)(k1v[s] & 1023u);
      fl[p][7 + s] = tss + nt - 1 - (int)(k2v[s] & 1023u);
    }
  }
  __syncthreads();
  int m = nfl;
  int wave = t >> 6, lane = t & 63;
  int c = lane >> 2, dg = lane & 3;
  for (int i = wave; i < m; i += 4) {
    int fq = fl[i][0];
    int code = (c < 12) ? fl[i][1 + c] : fl[i][1];
    const float* er = emb + code * 64 + dg * 16;
    const float* fr = fn + fq * 64 + dg * 16;
    double d = 0.0;
#pragma unroll
    for (int k = 0; k < 16; k++) d += (double)er[k] * (double)fr[k];
    d += __shfl_xor(d, 1, 64);  // same summation tree as k_fix_full
    d += __shfl_xor(d, 2, 64);
    unsigned long long key =
        ((unsigned long long)__double_as_longlong(d + 2.0) & ~0xFFFULL) |
        (unsigned long long)(4095 - code);
    if (c >= 12) key = 0ull;
#pragma unroll
    for (int off = 4; off <= 32; off <<= 1) {
      unsigned long long o = __shfl_xor(key, off, 64);
      key = key > o ? key : o;
    }
    if (lane == 0) idxw[fq] = 4095 - (int)(key & 0xFFFULL);
  }
}

// ---------------- exact fp64 full rescan (rare danger queries) --------------
// 1024 blocks = 16 code-chunks x 64 q-lanes; code row staged in registers once.
__global__ __launch_bounds__(256) void k_fix_full(const int* __restrict__ cnts,
                                                  const int* __restrict__ full,
                                                  const float* __restrict__ fn,
                                                  const float* __restrict__ emb,
                                                  unsigned long long* __restrict__ fullkey) {
  __shared__ float sfn[64];
  __shared__ unsigned long long red[256];
  int t = threadIdx.x;
  int chunk = blockIdx.x & 15;           // 16 chunks of 256 codes
  int c = chunk * 256 + t;               // this thread's code, fixed
  // stage code row into registers once (static indexing -> no scratch)
  float cr[64];
  {
    const float4v* er4 = (const float4v*)(emb + c * 64);
#pragma unroll
    for (int kk = 0; kk < 16; kk++) {
      float4v v = er4[kk];
      cr[kk * 4 + 0] = v[0];
      cr[kk * 4 + 1] = v[1];
      cr[kk * 4 + 2] = v[2];
      cr[kk * 4 + 3] = v[3];
    }
  }
  int total = cnts[0];
  total = total < N_TOK ? total : N_TOK;  // clamp vs stale replay state
  int qstride = (int)(gridDim.x >> 4);    // 64 q-lanes
  for (int w = (int)(blockIdx.x >> 4); w < total; w += qstride) {
    int q = full[w];
    __syncthreads();
    if (t < 64) sfn[t] = fn[q * 64 + t];
    __syncthreads();
    double s0 = 0, s1 = 0, s2 = 0, s3 = 0;
#pragma unroll
    for (int k = 0; k < 16; k++) {
      s0 += (double)cr[k] * (double)sfn[k];
      s1 += (double)cr[k + 16] * (double)sfn[k + 16];
      s2 += (double)cr[k + 32] * (double)sfn[k + 32];
      s3 += (double)cr[k + 48] * (double)sfn[k + 48];
    }
    double d = (s0 + s1) + (s2 + s3);
    unsigned long long key =
        ((unsigned long long)__double_as_longlong(d + 2.0) & ~0xFFFULL) |
        (unsigned long long)(4095 - c);
    red[t] = key;
    __syncthreads();
    for (int s = 128; s > 0; s >>= 1) {
      if (t < s) red[t] = red[t] > red[t + s] ? red[t] : red[t + s];
      __syncthreads();
    }
    if (t == 0) atomicMax(&fullkey[q], red[0]);
  }
}

// ---------------- write z_q, z_q_st, indices + scatter stats ----------------
// Wave-per-token scalar form (R9's float4/4-token rewrite regressed ~18us via
// the scattered-row atomic pattern; reverted R10, do not re-vectorize).
__global__ __launch_bounds__(256) void k_write_scatter(const int* __restrict__ idxw,
                                                       const unsigned long long* __restrict__ fullkey,
                                                       const float* __restrict__ z_e,
                                                       const float* __restrict__ emb,
                                                       const float* __restrict__ fn,
                                                       float* __restrict__ out,
                                                       float* __restrict__ esum,
                                                       float* __restrict__ usage) {
  int t = threadIdx.x;
  int nn = blockIdx.x * 4 + (t >> 6);
  int lane = t & 63;
  unsigned long long fk = fullkey[nn];
  int bi = fk ? (4095 - (int)(fk & 0xFFFULL)) : idxw[nn];
  float v = emb[bi * 64 + lane];
  float ze = z_e[nn * 64 + lane];
  out[OFF_ZQST + nn * 64 + lane] = ze + (v - ze);
  out[OFF_ZQ + nn * 64 + lane] = v;
  atomicAdd(&esum[bi * 64 + lane], fn[nn * 64 + lane]);
  if (lane == 0) {
    out[OFF_IDX + nn] = (float)bi;
    atomicAdd(&usage[bi], 1.0f);
  }
}

// ---------------- new_cs, new_ema_emb, new_embedding + fused stats ----------
// Block 1024 computes entropy/dead over usage and writes out[STATS] directly;
// blocks 0..1023 need only scal[2] (n), precomputed by k_prep.
__global__ __launch_bounds__(256) void k_final(const float* __restrict__ usage,
                                               const float* __restrict__ ema_cs,
                                               const float* __restrict__ ema_emb,
                                               const float* __restrict__ esum,
                                               const float* __restrict__ fn,
                                               const int* __restrict__ ridx,
                                               const float* __restrict__ scal,
                                               float* __restrict__ out) {
  int t = threadIdx.x;
  if (blockIdx.x == 1024) {  // fused stats block
    __shared__ float rE[4], rD[4];
    float ent = 0.f, dead = 0.f;
#pragma unroll
    for (int j = 0; j < 16; j++) {
      float u = usage[j * 256 + t];
      float p = u * (1.0f / 32768.0f);
      ent += (p > 0.f) ? p * logf(p) : 0.f;
      dead += (u == 0.f) ? 1.f : 0.f;
    }
    ent = wave_sum(ent);
    dead = wave_sum(dead);
    int w = t >> 6, lane = t & 63;
    if (lane == 0) { rE[w] = ent; rD[w] = dead; }
    __syncthreads();
    if (t == 0) {
      out[OFF_STATS + 0] = expf(-(rE[0] + rE[1] + rE[2] + rE[3]));
      out[OFF_STATS + 1] = (rD[0] + rD[1] + rD[2] + rD[3]) * (1.0f / 4096.0f);
    }
    return;
  }
  int k = blockIdx.x * 4 + (t >> 6);
  int lane = t & 63;
  float u = usage[k];
  float ncs = 0.99f * ema_cs[k] + 0.01f * u;
  if (lane == 0) out[OFF_NEWCS + k] = ncs;
  float nee = 0.99f * ema_emb[k * 64 + lane] + 0.01f * esum[k * 64 + lane];
  out[OFF_NEWEMA + k * 64 + lane] = nee;

  float n = scal[2];
  float smoothed = (ncs + 1e-5f) / (n + 4096.0f * 1e-5f);
  float ne = nee / fmaxf(smoothed, 1e-5f);
  float ss = wave_sum(ne * ne);
  ne = ne / fmaxf(sqrtf(ss), 1e-8f);

  float res;
  if (u <= 0.f) {
    int rsrc = ridx[k];
    float v = fn[rsrc * 64 + lane];
    float s2 = wave_sum(v * v);
    res = v / fmaxf(sqrtf(s2), 1e-8f);
  } else {
    res = ne;
  }
  out[OFF_NEWEMB + k * 64 + lane] = res;
}

extern "C" void kernel_launch(void* const* d_in, const int* in_sizes, int n_in,
                              void* d_out, int out_size, void* d_ws, size_t ws_size,
                              hipStream_t stream) {
  const float* z_e = (const float*)d_in[0];
  const float* emb = (const float*)d_in[1];
  const float* ema_cs = (const float*)d_in[2];
  const float* ema_emb = (const float*)d_in[3];
  float* out = (float*)d_out;
  char* ws = (char*)d_ws;

  float* fn = (float*)(ws + WS_FN);
  float* esum = (float*)(ws + WS_ESUM);
  float* usage = (float*)(ws + WS_USAGE);
  int* cnts = (int*)(ws + WS_CNTS);
  float* scal = (float*)(ws + WS_CNTS + 16);
  unsigned long long* fullkey = (unsigned long long*)(ws + WS_FULLKEY);
  unsigned short* ehi = (unsigned short*)(ws + WS_EHI);
  unsigned short* elo = (unsigned short*)(ws + WS_ELO);
  unsigned* pk1 = (unsigned*)(ws + WS_PK1);
  unsigned* pk2 = (unsigned*)(ws + WS_PK2);
  int* idxw = (int*)(ws + WS_IDXW);
  int* ridx = (int*)(ws + WS_RIDX);
  int* full = (int*)(ws + WS_FULL);
  unsigned short* fnhi = (unsigned short*)(ws + WS_FNHI);
  unsigned short* fnlo = (unsigned short*)(ws + WS_FNLO);

  k_prep<<<2573, 256, 0, stream>>>(z_e, emb, ema_cs, fn, fnhi, fnlo, ehi, elo,
                                   ridx, (int*)(ws + WS_ESUM), scal);
  k_dots<<<dim3(256, SPLITS), 256, 0, stream>>>(fnhi, fnlo, ehi, elo, pk1, pk2);
  k_merge_fix<<<128, 256, 0, stream>>>(pk1, pk2, fn, emb, idxw, cnts, full, fullkey);
  k_fix_full<<<1024, 256, 0, stream>>>(cnts, full, fn, emb, fullkey);
  k_write_scatter<<<8192, 256, 0, stream>>>(idxw, fullkey, z_e, emb, fn, out, esum, usage);
  k_final<<<1025, 256, 0, stream>>>(usage, ema_cs, ema_emb, esum, fn, ridx, scal, out);
}

// Round 13
// 147.876 us; speedup vs baseline: 1.0432x; 1.0432x over previous
//
#include <hip/hip_runtime.h>
#include <math.h>

// Problem constants
#define N_TOK 32768
#define KCB   4096
#define SPLITS 6
// per-split tile counts (even): {44,44,42,42,42,42}, sum = 256 tiles = 4096 codes

// Output layout (flat float32)
#define OFF_ZQST   0
#define OFF_ZQ     2097152
#define OFF_IDX    4194304
#define OFF_STATS  4227072
#define OFF_NEWEMB 4227074
#define OFF_NEWCS  4489218
#define OFF_NEWEMA 4493314

// Workspace layout (bytes)
#define WS_FN       0          // 8388608
#define WS_ESUM     8388608    // 1048576 (zeroed by k_prep)
#define WS_USAGE    9437184    // 16384   (zeroed by k_prep)
#define WS_CNTS     9453568    // 1024    (zeroed by k_prep; cnts[0]=fullcnt, scal[] at +16)
#define WS_FULLKEY  9454592    // 262144  (init by k_merge_fix)
#define WS_EHI      9716736    // 524288
#define WS_ELO      10241024   // 524288
#define WS_PK1      10765312   // 786432 (6 splits)
#define WS_PK2      11551744   // 786432
#define WS_IDXW     12338176   // 131072
#define WS_RIDX     12469248   // 16384
#define WS_FULL     12485632   // 131072
#define WS_FNHI     12616704   // 4194304 (pre-split bf16 hi of fn*0.25)
#define WS_FNLO     16811008   // 4194304 (bf16 lo)
// total workspace = 21005312

// 131072 keys = 128 x-ulps dot gap
#define THRKEY 131072u
// danger margin for hidden-3rd-in-split
#define DGRKEY 98304u

typedef __attribute__((ext_vector_type(8))) short short8;
typedef __attribute__((ext_vector_type(4))) short short4v;
typedef __attribute__((ext_vector_type(4))) float float4v;
typedef __attribute__((ext_vector_type(4))) int int4v;

__device__ __forceinline__ float wave_sum(float v) {
#pragma unroll
  for (int off = 32; off > 0; off >>= 1) v += __shfl_xor(v, off, 64);
  return v;
}

// round-to-nearest-even f32 -> bf16 bits
__device__ __forceinline__ unsigned short f2bf(float f) {
  unsigned u = __float_as_uint(f);
  unsigned r = (u + 0x7fffu + ((u >> 16) & 1u)) >> 16;
  return (unsigned short)r;
}
__device__ __forceinline__ float bf2f(unsigned short h) {
  return __uint_as_float(((unsigned)h) << 16);
}

// async global->LDS 16B/lane (dest = wave-uniform base + lane*16)
typedef const __attribute__((address_space(1))) unsigned int* gas_ptr;
typedef __attribute__((address_space(3))) unsigned int* las_ptr;
__device__ __forceinline__ void gl_lds16(const void* g, void* l) {
  __builtin_amdgcn_global_load_lds((gas_ptr)g, (las_ptr)l, 16, 0, 0);
}

// exact top-2 running update: run2' = median(run1, run2, kb)  [run1 >= run2]
__device__ __forceinline__ unsigned med3u(unsigned a, unsigned b, unsigned c) {
  unsigned r;
  asm("v_med3_u32 %0, %1, %2, %3" : "=v"(r) : "v"(a), "v"(b), "v"(c));
  return r;
}

// ---------------- Threefry-2x32 (20 rounds), bit-exact vs JAX ----------------
__device__ __forceinline__ unsigned rotl32(unsigned x, int d) {
  return (x << d) | (x >> (32 - d));
}
__device__ __forceinline__ void tf2x32(unsigned k0, unsigned k1,
                                       unsigned x0, unsigned x1,
                                       unsigned& o0, unsigned& o1) {
  unsigned ks2 = k0 ^ k1 ^ 0x1BD11BDAu;
  unsigned v0 = x0 + k0, v1 = x1 + k1;
  v0 += v1; v1 = rotl32(v1, 13) ^ v0;
  v0 += v1; v1 = rotl32(v1, 15) ^ v0;
  v0 += v1; v1 = rotl32(v1, 26) ^ v0;
  v0 += v1; v1 = rotl32(v1, 6) ^ v0;
  v0 += k1; v1 += ks2 + 1u;
  v0 += v1; v1 = rotl32(v1, 17) ^ v0;
  v0 += v1; v1 = rotl32(v1, 29) ^ v0;
  v0 += v1; v1 = rotl32(v1, 16) ^ v0;
  v0 += v1; v1 = rotl32(v1, 24) ^ v0;
  v0 += ks2; v1 += k0 + 2u;
  v0 += v1; v1 = rotl32(v1, 13) ^ v0;
  v0 += v1; v1 = rotl32(v1, 15) ^ v0;
  v0 += v1; v1 = rotl32(v1, 26) ^ v0;
  v0 += v1; v1 = rotl32(v1, 6) ^ v0;
  v0 += k0; v1 += k1 + 3u;
  v0 += v1; v1 = rotl32(v1, 17) ^ v0;
  v0 += v1; v1 = rotl32(v1, 29) ^ v0;
  v0 += v1; v1 = rotl32(v1, 16) ^ v0;
  v0 += v1; v1 = rotl32(v1, 24) ^ v0;
  v0 += k1; v1 += ks2 + 4u;
  v0 += v1; v1 = rotl32(v1, 13) ^ v0;
  v0 += v1; v1 = rotl32(v1, 15) ^ v0;
  v0 += v1; v1 = rotl32(v1, 26) ^ v0;
  v0 += v1; v1 = rotl32(v1, 6) ^ v0;
  v0 += ks2; v1 += k0 + 5u;
  o0 = v0; o1 = v1;
}

// ---- fused prep (float4-vectorized, G13): norm | emb hi/lo | ridx |
//      zero | ema_cs sum (scal[2]) | fn hi/lo bf16 pre-split ----
__global__ __launch_bounds__(256) void k_prep(const float* __restrict__ z_e,
                                              const float* __restrict__ emb,
                                              const float* __restrict__ ema_cs,
                                              float* __restrict__ fn,
                                              unsigned short* __restrict__ fnhi,
                                              unsigned short* __restrict__ fnlo,
                                              unsigned short* __restrict__ ehi,
                                              unsigned short* __restrict__ elo,
                                              int* __restrict__ ridx,
                                              int* __restrict__ zbase,
                                              float* __restrict__ scal) {
  __shared__ float rC[4];
  int b = blockIdx.x;
  int t = threadIdx.x;
  if (b < 2048) {
    int wave = t >> 6, lane = t & 63;
    int grp = lane >> 4, l = lane & 15;          // 4 rows/wave, 16 lanes/row
    int n = b * 16 + wave * 4 + grp;
    float4v v = ((const float4v*)(z_e + n * 64))[l];
    // exact replica of the old 64-lane butterfly tree
    float4v p;
#pragma unroll
    for (int j = 0; j < 4; j++) p[j] = v[j] * v[j];
#pragma unroll
    for (int j = 0; j < 4; j++) p[j] += __shfl_xor(p[j], 8, 64);   // elems +-32
#pragma unroll
    for (int j = 0; j < 4; j++) p[j] += __shfl_xor(p[j], 4, 64);   // +-16
#pragma unroll
    for (int j = 0; j < 4; j++) p[j] += __shfl_xor(p[j], 2, 64);   // +-8
#pragma unroll
    for (int j = 0; j < 4; j++) p[j] += __shfl_xor(p[j], 1, 64);   // +-4
    float t0 = p[0] + p[2], t1 = p[1] + p[3];                      // +-2
    float ss = t0 + t1;                                            // +-1
    float d = fmaxf(sqrtf(ss), 1e-8f);
    float4v o;
#pragma unroll
    for (int j = 0; j < 4; j++) o[j] = v[j] / d;
    ((float4v*)(fn + n * 64))[l] = o;
    // bf16 hi/lo split of o*0.25 (exact pow2), same ops k_dots used
    short4v fh, fl2;
#pragma unroll
    for (int j = 0; j < 4; j++) {
      float f = o[j] * 0.25f;
      unsigned short hu = f2bf(f);
      fh[j] = (short)hu;
      fl2[j] = (short)f2bf(f - bf2f(hu));
    }
    ((short4v*)(fnhi + n * 64))[l] = fh;
    ((short4v*)(fnlo + n * 64))[l] = fl2;
  } else if (b < 2304) {
    int i = (b - 2048) * 1024 + t * 4;
    float4v x = *(const float4v*)(emb + i);
    short4v hh, ll;
#pragma unroll
    for (int j = 0; j < 4; j++) {
      unsigned short hu = f2bf(x[j]);
      hh[j] = (short)hu;
      ll[j] = (short)f2bf(x[j] - bf2f(hu));
    }
    *(short4v*)(ehi + i) = hh;
    *(short4v*)(elo + i) = ll;
  } else if (b < 2312) {
    int j = (b - 2304) * 256 + t;  // 0..2047
    unsigned a0, b0, a1, b1;
    tf2x32(0u, 1u, 0u, 2u, a0, b0);
    tf2x32(0u, 1u, 1u, 3u, a1, b1);
    unsigned o0, o1;
    tf2x32(b0, b1, (unsigned)j, (unsigned)(j + 2048), o0, o1);
    ridx[j] = (int)(o0 & 32767u);
    ridx[j + 2048] = (int)(o1 & 32767u);
  } else {
    // zero esum+usage+cnts/scal = 266496 ints = 66624 int4 -> blocks 2312..2572
    int i4 = (b - 2312) * 256 + t;
    if (i4 < 66624) ((int4v*)zbase)[i4] = (int4v){0, 0, 0, 0};
    if (b == 2572) {
      __syncthreads();  // zeros of this block's range (incl. scal) are done
      float s = 0.f;
#pragma unroll
      for (int j = 0; j < 16; j++) s += ema_cs[j * 256 + t];
      s = wave_sum(s);
      int w = t >> 6, lane = t & 63;
      if (lane == 0) rC[w] = s;
      __syncthreads();
      if (t == 0) scal[2] = 0.99f * (rC[0] + rC[1] + rC[2] + rC[3]) + 327.68f;
    }
  }
}

// ---------------- MFMA dots + per-split packed top-2 (R11 kernel) -----------
// 3-pass bf16 double-double (A scaled 0.25): lo*Hi + hi*Lo + hi*Hi.
// R7: block-shared LDS staging of the B-stream (global_load_lds, swizzled),
// double-buffered, 1 barrier/pair.  R8: med3 top-2 update.  R11: A fragments
// pre-split in k_prep (fnhi/fnlo) -> 16 short8 loads, zero conversion VALU.
// STRUCTURE LESSONS: (R2-R4) launch_bounds (256,3) -> no spill, do not
// tighten.  (R12) do NOT split the tile range across waves/blocks: the
// 256-query 4-wave block is load-bearing (4x B-stream sharing); halving
// per-wave work halves amortization and adds masking overhead (+14%) while
// occupancy barely moves.  This exact kernel measured 53.0us.
__global__ __launch_bounds__(256, 3) void k_dots(const unsigned short* __restrict__ fnhi,
                                                 const unsigned short* __restrict__ fnlo,
                                                 const unsigned short* __restrict__ ehi,
                                                 const unsigned short* __restrict__ elo,
                                                 unsigned* __restrict__ pk1,
                                                 unsigned* __restrict__ pk2) {
  __shared__ unsigned short lds_b[2][2][2][1024];  // [buf][tileInPair][hi/lo][2KB]
  int t = threadIdx.x;
  int wave = t >> 6, lane = t & 63;
  int g = lane >> 4, n = lane & 15;
  int qw = blockIdx.x * 256 + wave * 64;  // wave's 64 queries
  int split = blockIdx.y;                 // 0..5
  int nt16 = (split < 2) ? 704 : 672;     // codes in this split
  int tstart16 = (split < 3) ? 704 * split : 672 * split + 64;
  int ntiles = nt16 >> 4;                 // 44 or 42 (even)
  int npairs = ntiles >> 1;               // 22 or 21

  // A fragments: direct short8 loads of the pre-split hi/lo
  short8 ahi[4][2], alo[4][2];
#pragma unroll
  for (int s = 0; s < 4; s++)
#pragma unroll
    for (int ks = 0; ks < 2; ks++) {
      int off = (qw + s * 16 + n) * 64 + ks * 32 + g * 8;
      ahi[s][ks] = *(const short8*)(fnhi + off);
      alo[s][ks] = *(const short8*)(fnlo + off);
    }

  unsigned run1[4][4], run2[4][4];
#pragma unroll
  for (int s = 0; s < 4; s++)
#pragma unroll
    for (int r = 0; r < 4; r++) { run1[s][r] = 0u; run2[s][r] = 0u; }

  const float hiclamp = __uint_as_float(0x3F9FFFFFu);  // 1.25 - 1ulp

  // staging role: wave -> (tile in pair, hi/lo stream); 2 x 1KB per wave/pair
  int stile = wave >> 1;
  int shl = wave & 1;
  const unsigned short* sbase = shl ? elo : ehi;
  int c0 = lane ^ ((lane >> 3) & 7);  // inverse-swizzled source chunk (involution)

#define STAGE(BUF, PAIR)                                                        \
    {                                                                           \
      const unsigned short* sg =                                                \
          sbase + (tstart16 + ((PAIR) * 2 + stile) * 16) * 64;                  \
      gl_lds16(sg + c0 * 8, &lds_b[BUF][stile][shl][0]);                        \
      gl_lds16(sg + 512 + c0 * 8, &lds_b[BUF][stile][shl][512]);                \
    }

  // swizzled read slots (shorts): lane (g,n) wants linear chunk n*8+g (+4 for H1)
  int sh0 = (n * 8 + (g ^ (n & 7))) * 8;
  int sh1 = (n * 8 + ((g + 4) ^ (n & 7))) * 8;

#define MFMA_BLOCK(H0, H1, L0, L1)                                              \
    float4v a0 = (float4v){1.125f, 1.125f, 1.125f, 1.125f};                     \
    float4v a1 = a0, a2 = a0, a3 = a0;                                          \
    a0 = __builtin_amdgcn_mfma_f32_16x16x32_bf16(alo[0][0], H0, a0, 0, 0, 0);   \
    a1 = __builtin_amdgcn_mfma_f32_16x16x32_bf16(alo[1][0], H0, a1, 0, 0, 0);   \
    a2 = __builtin_amdgcn_mfma_f32_16x16x32_bf16(alo[2][0], H0, a2, 0, 0, 0);   \
    a3 = __builtin_amdgcn_mfma_f32_16x16x32_bf16(alo[3][0], H0, a3, 0, 0, 0);   \
    a0 = __builtin_amdgcn_mfma_f32_16x16x32_bf16(alo[0][1], H1, a0, 0, 0, 0);   \
    a1 = __builtin_amdgcn_mfma_f32_16x16x32_bf16(alo[1][1], H1, a1, 0, 0, 0);   \
    a2 = __builtin_amdgcn_mfma_f32_16x16x32_bf16(alo[2][1], H1, a2, 0, 0, 0);   \
    a3 = __builtin_amdgcn_mfma_f32_16x16x32_bf16(alo[3][1], H1, a3, 0, 0, 0);   \
    a0 = __builtin_amdgcn_mfma_f32_16x16x32_bf16(ahi[0][0], L0, a0, 0, 0, 0);   \
    a1 = __builtin_amdgcn_mfma_f32_16x16x32_bf16(ahi[1][0], L0, a1, 0, 0, 0);   \
    a2 = __builtin_amdgcn_mfma_f32_16x16x32_bf16(ahi[2][0], L0, a2, 0, 0, 0);   \
    a3 = __builtin_amdgcn_mfma_f32_16x16x32_bf16(ahi[3][0], L0, a3, 0, 0, 0);   \
    a0 = __builtin_amdgcn_mfma_f32_16x16x32_bf16(ahi[0][1], L1, a0, 0, 0, 0);   \
    a1 = __builtin_amdgcn_mfma_f32_16x16x32_bf16(ahi[1][1], L1, a1, 0, 0, 0);   \
    a2 = __builtin_amdgcn_mfma_f32_16x16x32_bf16(ahi[2][1], L1, a2, 0, 0, 0);   \
    a3 = __builtin_amdgcn_mfma_f32_16x16x32_bf16(ahi[3][1], L1, a3, 0, 0, 0);   \
    a0 = __builtin_amdgcn_mfma_f32_16x16x32_bf16(ahi[0][0], H0, a0, 0, 0, 0);   \
    a1 = __builtin_amdgcn_mfma_f32_16x16x32_bf16(ahi[1][0], H0, a1, 0, 0, 0);   \
    a2 = __builtin_amdgcn_mfma_f32_16x16x32_bf16(ahi[2][0], H0, a2, 0, 0, 0);   \
    a3 = __builtin_amdgcn_mfma_f32_16x16x32_bf16(ahi[3][0], H0, a3, 0, 0, 0);   \
    a0 = __builtin_amdgcn_mfma_f32_16x16x32_bf16(ahi[0][1], H1, a0, 0, 0, 0);   \
    a1 = __builtin_amdgcn_mfma_f32_16x16x32_bf16(ahi[1][1], H1, a1, 0, 0, 0);   \
    a2 = __builtin_amdgcn_mfma_f32_16x16x32_bf16(ahi[2][1], H1, a2, 0, 0, 0);   \
    a3 = __builtin_amdgcn_mfma_f32_16x16x32_bf16(ahi[3][1], H1, a3, 0, 0, 0);

#define SELECT_BLOCK(KT)                                                        \
    {                                                                           \
      unsigned invb = (unsigned)(nt16 - 1 - (KT) * 16 - n);                     \
      _Pragma("unroll") for (int r = 0; r < 4; r++) {                           \
        float x0 = __builtin_amdgcn_fmed3f(a0[r], 1.0f, hiclamp);               \
        unsigned kb0 = (__float_as_uint(x0) << 10) + invb;                      \
        run2[0][r] = med3u(run1[0][r], run2[0][r], kb0);                        \
        run1[0][r] = max(run1[0][r], kb0);                                      \
        float x1 = __builtin_amdgcn_fmed3f(a1[r], 1.0f, hiclamp);               \
        unsigned kb1 = (__float_as_uint(x1) << 10) + invb;                      \
        run2[1][r] = med3u(run1[1][r], run2[1][r], kb1);                        \
        run1[1][r] = max(run1[1][r], kb1);                                      \
        float x2 = __builtin_amdgcn_fmed3f(a2[r], 1.0f, hiclamp);               \
        unsigned kb2 = (__float_as_uint(x2) << 10) + invb;                      \
        run2[2][r] = med3u(run1[2][r], run2[2][r], kb2);                        \
        run1[2][r] = max(run1[2][r], kb2);                                      \
        float x3 = __builtin_amdgcn_fmed3f(a3[r], 1.0f, hiclamp);               \
        unsigned kb3 = (__float_as_uint(x3) << 10) + invb;                      \
        run2[3][r] = med3u(run1[3][r], run2[3][r], kb3);                        \
        run1[3][r] = max(run1[3][r], kb3);                                      \
      }                                                                         \
    }

  STAGE(0, 0)
  __syncthreads();  // drains vmcnt -> buf0 staged
  int bb = 0;
#pragma unroll 1
  for (int p = 0; p < npairs; p++) {
    if (p + 1 < npairs) STAGE(bb ^ 1, p + 1)  // async into other buffer
    {
      short8 H0 = *(const short8*)&lds_b[bb][0][0][sh0];
      short8 H1 = *(const short8*)&lds_b[bb][0][0][sh1];
      short8 L0 = *(const short8*)&lds_b[bb][0][1][sh0];
      short8 L1 = *(const short8*)&lds_b[bb][0][1][sh1];
      MFMA_BLOCK(H0, H1, L0, L1)
      SELECT_BLOCK(p * 2)
    }
    {
      short8 H0 = *(const short8*)&lds_b[bb][1][0][sh0];
      short8 H1 = *(const short8*)&lds_b[bb][1][0][sh1];
      short8 L0 = *(const short8*)&lds_b[bb][1][1][sh0];
      short8 L1 = *(const short8*)&lds_b[bb][1][1][sh1];
      MFMA_BLOCK(H0, H1, L0, L1)
      SELECT_BLOCK(p * 2 + 1)
    }
    __syncthreads();  // drains stage of p+1; all waves done reading bb
    bb ^= 1;
  }
#undef MFMA_BLOCK
#undef SELECT_BLOCK
#undef STAGE

  // butterfly top-2 merge across the 16 n-lanes
#pragma unroll
  for (int off = 1; off <= 8; off <<= 1) {
#pragma unroll
    for (int s = 0; s < 4; s++)
#pragma unroll
      for (int r = 0; r < 4; r++) {
        unsigned o1 = (unsigned)__shfl_xor((int)run1[s][r], off, 64);
        unsigned o2 = (unsigned)__shfl_xor((int)run2[s][r], off, 64);
        run2[s][r] = max(min(run1[s][r], o1), max(run2[s][r], o2));
        run1[s][r] = max(run1[s][r], o1);
      }
  }

  if (n == 0) {
#pragma unroll
    for (int s = 0; s < 4; s++)
#pragma unroll
      for (int r = 0; r < 4; r++) {
        int q = qw + s * 16 + g * 4 + r;
        pk1[split * N_TOK + q] = run1[s][r];
        pk2[split * N_TOK + q] = run2[s][r];
      }
  }
}

// ---- merge splits + in-kernel fp64 rescore of 12 candidates for flagged ----
// danger (possible hidden 3rd-in-split near max) -> rare full-rescan list.
__global__ __launch_bounds__(256) void k_merge_fix(const unsigned* __restrict__ pk1,
                                                   const unsigned* __restrict__ pk2,
                                                   const float* __restrict__ fn,
                                                   const float* __restrict__ emb,
                                                   int* __restrict__ idxw,
                                                   int* __restrict__ cnts,
                                                   int* __restrict__ full,
                                                   unsigned long long* __restrict__ fullkey) {
  __shared__ int nfl;
  __shared__ int fl[256][13];
  int t = threadIdx.x;
  if (t == 0) nfl = 0;
  __syncthreads();
  int q = blockIdx.x * 256 + t;
  unsigned k1v[SPLITS], k2v[SPLITS];
  unsigned b1 = 0u, b2 = 0u;
  int s1 = 0;
#pragma unroll
  for (int s = 0; s < SPLITS; s++) {
    unsigned k1 = pk1[s * N_TOK + q];
    unsigned k2 = pk2[s * N_TOK + q];
    k1v[s] = k1;
    k2v[s] = k2;
    b2 = max(b2, min(b1, k1));
    b2 = max(b2, k2);
    if (k1 > b1) { b1 = k1; s1 = s; }
  }
  int nt16s = (s1 < 2) ? 704 : 672;
  int ts16 = (s1 < 3) ? 704 * s1 : 672 * s1 + 64;
  idxw[q] = ts16 + nt16s - 1 - (int)(b1 & 1023u);
  fullkey[q] = 0ull;
  bool danger = false;
#pragma unroll
  for (int s = 0; s < SPLITS; s++) danger |= (k2v[s] + DGRKEY > b1);
  if (danger) {
    int p = atomicAdd(&cnts[0], 1);
    full[p] = q;
  } else if (b1 - b2 < THRKEY) {
    int p = atomicAdd(&nfl, 1);
    fl[p][0] = q;
#pragma unroll
    for (int s = 0; s < SPLITS; s++) {
      int nt = (s < 2) ? 704 : 672;
      int tss = (s < 3) ? 704 * s : 672 * s + 64;
      fl[p][1 + s] = tss + nt - 1 - (int)(k1v[s] & 1023u);
      fl[p][7 + s] = tss + nt - 1 - (int)(k2v[s] & 1023u);
    }
  }
  __syncthreads();
  int m = nfl;
  int wave = t >> 6, lane = t & 63;
  int c = lane >> 2, dg = lane & 3;
  for (int i = wave; i < m; i += 4) {
    int fq = fl[i][0];
    int code = (c < 12) ? fl[i][1 + c] : fl[i][1];
    const float* er = emb + code * 64 + dg * 16;
    const float* fr = fn + fq * 64 + dg * 16;
    double d = 0.0;
#pragma unroll
    for (int k = 0; k < 16; k++) d += (double)er[k] * (double)fr[k];
    d += __shfl_xor(d, 1, 64);  // same summation tree as k_fix_full
    d += __shfl_xor(d, 2, 64);
    unsigned long long key =
        ((unsigned long long)__double_as_longlong(d + 2.0) & ~0xFFFULL) |
        (unsigned long long)(4095 - code);
    if (c >= 12) key = 0ull;
#pragma unroll
    for (int off = 4; off <= 32; off <<= 1) {
      unsigned long long o = __shfl_xor(key, off, 64);
      key = key > o ? key : o;
    }
    if (lane == 0) idxw[fq] = 4095 - (int)(key & 0xFFFULL);
  }
}

// ---------------- exact fp64 full rescan (rare danger queries) --------------
// 1024 blocks = 16 code-chunks x 64 q-lanes; code row staged in registers once.
__global__ __launch_bounds__(256) void k_fix_full(const int* __restrict__ cnts,
                                                  const int* __restrict__ full,
                                                  const float* __restrict__ fn,
                                                  const float* __restrict__ emb,
                                                  unsigned long long* __restrict__ fullkey) {
  __shared__ float sfn[64];
  __shared__ unsigned long long red[256];
  int t = threadIdx.x;
  int chunk = blockIdx.x & 15;           // 16 chunks of 256 codes
  int c = chunk * 256 + t;               // this thread's code, fixed
  // stage code row into registers once (static indexing -> no scratch)
  float cr[64];
  {
    const float4v* er4 = (const float4v*)(emb + c * 64);
#pragma unroll
    for (int kk = 0; kk < 16; kk++) {
      float4v v = er4[kk];
      cr[kk * 4 + 0] = v[0];
      cr[kk * 4 + 1] = v[1];
      cr[kk * 4 + 2] = v[2];
      cr[kk * 4 + 3] = v[3];
    }
  }
  int total = cnts[0];
  total = total < N_TOK ? total : N_TOK;  // clamp vs stale replay state
  int qstride = (int)(gridDim.x >> 4);    // 64 q-lanes
  for (int w = (int)(blockIdx.x >> 4); w < total; w += qstride) {
    int q = full[w];
    __syncthreads();
    if (t < 64) sfn[t] = fn[q * 64 + t];
    __syncthreads();
    double s0 = 0, s1 = 0, s2 = 0, s3 = 0;
#pragma unroll
    for (int k = 0; k < 16; k++) {
      s0 += (double)cr[k] * (double)sfn[k];
      s1 += (double)cr[k + 16] * (double)sfn[k + 16];
      s2 += (double)cr[k + 32] * (double)sfn[k + 32];
      s3 += (double)cr[k + 48] * (double)sfn[k + 48];
    }
    double d = (s0 + s1) + (s2 + s3);
    unsigned long long key =
        ((unsigned long long)__double_as_longlong(d + 2.0) & ~0xFFFULL) |
        (unsigned long long)(4095 - c);
    red[t] = key;
    __syncthreads();
    for (int s = 128; s > 0; s >>= 1) {
      if (t < s) red[t] = red[t] > red[t + s] ? red[t] : red[t + s];
      __syncthreads();
    }
    if (t == 0) atomicMax(&fullkey[q], red[0]);
  }
}

// ---------------- write z_q, z_q_st, indices + scatter stats ----------------
// Wave-per-token scalar form (R9's float4/4-token rewrite regressed ~18us via
// the scattered-row atomic pattern; reverted R10, do not re-vectorize).
__global__ __launch_bounds__(256) void k_write_scatter(const int* __restrict__ idxw,
                                                       const unsigned long long* __restrict__ fullkey,
                                                       const float* __restrict__ z_e,
                                                       const float* __restrict__ emb,
                                                       const float* __restrict__ fn,
                                                       float* __restrict__ out,
                                                       float* __restrict__ esum,
                                                       float* __restrict__ usage) {
  int t = threadIdx.x;
  int nn = blockIdx.x * 4 + (t >> 6);
  int lane = t & 63;
  unsigned long long fk = fullkey[nn];
  int bi = fk ? (4095 - (int)(fk & 0xFFFULL)) : idxw[nn];
  float v = emb[bi * 64 + lane];
  float ze = z_e[nn * 64 + lane];
  out[OFF_ZQST + nn * 64 + lane] = ze + (v - ze);
  out[OFF_ZQ + nn * 64 + lane] = v;
  atomicAdd(&esum[bi * 64 + lane], fn[nn * 64 + lane]);
  if (lane == 0) {
    out[OFF_IDX + nn] = (float)bi;
    atomicAdd(&usage[bi], 1.0f);
  }
}

// ---------------- new_cs, new_ema_emb, new_embedding + fused stats ----------
// Block 1024 computes entropy/dead over usage and writes out[STATS] directly;
// blocks 0..1023 need only scal[2] (n), precomputed by k_prep.
__global__ __launch_bounds__(256) void k_final(const float* __restrict__ usage,
                                               const float* __restrict__ ema_cs,
                                               const float* __restrict__ ema_emb,
                                               const float* __restrict__ esum,
                                               const float* __restrict__ fn,
                                               const int* __restrict__ ridx,
                                               const float* __restrict__ scal,
                                               float* __restrict__ out) {
  int t = threadIdx.x;
  if (blockIdx.x == 1024) {  // fused stats block
    __shared__ float rE[4], rD[4];
    float ent = 0.f, dead = 0.f;
#pragma unroll
    for (int j = 0; j < 16; j++) {
      float u = usage[j * 256 + t];
      float p = u * (1.0f / 32768.0f);
      ent += (p > 0.f) ? p * logf(p) : 0.f;
      dead += (u == 0.f) ? 1.f : 0.f;
    }
    ent = wave_sum(ent);
    dead = wave_sum(dead);
    int w = t >> 6, lane = t & 63;
    if (lane == 0) { rE[w] = ent; rD[w] = dead; }
    __syncthreads();
    if (t == 0) {
      out[OFF_STATS + 0] = expf(-(rE[0] + rE[1] + rE[2] + rE[3]));
      out[OFF_STATS + 1] = (rD[0] + rD[1] + rD[2] + rD[3]) * (1.0f / 4096.0f);
    }
    return;
  }
  int k = blockIdx.x * 4 + (t >> 6);
  int lane = t & 63;
  float u = usage[k];
  float ncs = 0.99f * ema_cs[k] + 0.01f * u;
  if (lane == 0) out[OFF_NEWCS + k] = ncs;
  float nee = 0.99f * ema_emb[k * 64 + lane] + 0.01f * esum[k * 64 + lane];
  out[OFF_NEWEMA + k * 64 + lane] = nee;

  float n = scal[2];
  float smoothed = (ncs + 1e-5f) / (n + 4096.0f * 1e-5f);
  float ne = nee / fmaxf(smoothed, 1e-5f);
  float ss = wave_sum(ne * ne);
  ne = ne / fmaxf(sqrtf(ss), 1e-8f);

  float res;
  if (u <= 0.f) {
    int rsrc = ridx[k];
    float v = fn[rsrc * 64 + lane];
    float s2 = wave_sum(v * v);
    res = v / fmaxf(sqrtf(s2), 1e-8f);
  } else {
    res = ne;
  }
  out[OFF_NEWEMB + k * 64 + lane] = res;
}

extern "C" void kernel_launch(void* const* d_in, const int* in_sizes, int n_in,
                              void* d_out, int out_size, void* d_ws, size_t ws_size,
                              hipStream_t stream) {
  const float* z_e = (const float*)d_in[0];
  const float* emb = (const float*)d_in[1];
  const float* ema_cs = (const float*)d_in[2];
  const float* ema_emb = (const float*)d_in[3];
  float* out = (float*)d_out;
  char* ws = (char*)d_ws;

  float* fn = (float*)(ws + WS_FN);
  float* esum = (float*)(ws + WS_ESUM);
  float* usage = (float*)(ws + WS_USAGE);
  int* cnts = (int*)(ws + WS_CNTS);
  float* scal = (float*)(ws + WS_CNTS + 16);
  unsigned long long* fullkey = (unsigned long long*)(ws + WS_FULLKEY);
  unsigned short* ehi = (unsigned short*)(ws + WS_EHI);
  unsigned short* elo = (unsigned short*)(ws + WS_ELO);
  unsigned* pk1 = (unsigned*)(ws + WS_PK1);
  unsigned* pk2 = (unsigned*)(ws + WS_PK2);
  int* idxw = (int*)(ws + WS_IDXW);
  int* ridx = (int*)(ws + WS_RIDX);
  int* full = (int*)(ws + WS_FULL);
  unsigned short* fnhi = (unsigned short*)(ws + WS_FNHI);
  unsigned short* fnlo = (unsigned short*)(ws + WS_FNLO);

  k_prep<<<2573, 256, 0, stream>>>(z_e, emb, ema_cs, fn, fnhi, fnlo, ehi, elo,
                                   ridx, (int*)(ws + WS_ESUM), scal);
  k_dots<<<dim3(128, SPLITS), 256, 0, stream>>>(fnhi, fnlo, ehi, elo, pk1, pk2);
  k_merge_fix<<<128, 256, 0, stream>>>(pk1, pk2, fn, emb, idxw, cnts, full, fullkey);
  k_fix_full<<<1024, 256, 0, stream>>>(cnts, full, fn, emb, fullkey);
  k_write_scatter<<<8192, 256, 0, stream>>>(idxw, fullkey, z_e, emb, fn, out, esum, usage);
  k_final<<<1025, 256, 0, stream>>>(usage, ema_cs, ema_emb, esum, fn, ridx, scal, out);
}